// Round 3
// baseline (162.249 us; speedup 1.0000x reference)
//
#include <hip/hip_runtime.h>
#include <hip/hip_cooperative_groups.h>

namespace cg = cooperative_groups;

#define BQ 32
#define H  128
#define C  512
#define D  128

typedef _Float16 half8v __attribute__((ext_vector_type(8)));
typedef float floatx4 __attribute__((ext_vector_type(4)));

// ---------------------------------------------------------------------------
// Single cooperative kernel, grid 256 x 512 thr (1 block/CU, all co-resident).
// Rationale (r2 measurements): launch-boundary gap ~11us each; r0's three
// launches spent ~33us on gaps vs ~18us of kernel time.  This kernel fuses
// qprep + scores + loss with two grid.sync()s, leaving one launch.
//
// P1 keeps the ONLY Q transport the compiler provably pipelines (r2: fp32
// loads + cvt at use -> VGPR 96, rematerialized loads, 72us latency-bound):
// fp16 fragments prepared in P0, loaded as single half8v per frag into a
// 3-slot register ring at prefetch distance 2 (byte-identical r0 main loop).
// Block = two 4-wave c-groups (r1-verified cs/w4 mapping + epilogue).
// ---------------------------------------------------------------------------
__global__ __launch_bounds__(512, 2) void mono_kernel(const float* __restrict__ pos,
                                                      const float* __restrict__ q,
                                                      float* __restrict__ scores,
                                                      _Float16* __restrict__ qs,
                                                      float* __restrict__ out) {
  const int bx   = blockIdx.x;
  const int tid  = threadIdx.x;
  const int w    = tid >> 6;         // 0..7
  const int lane = tid & 63;
  const int cs   = w >> 2;           // which c of the block's pair
  const int w4   = w & 3;
  const int dq   = w4 & 1;           // d-half within c-group
  const int sh   = w4 >> 1;          // s-half within c-group
  const int quad = lane >> 4;
  const int nrow = lane & 15;

  __shared__ float pmm[2][BQ][4][16];   // [cs][b][w4][s_local]  16 KB
  __shared__ float red[8];

  // ---- P0: Q fp32 -> fp16 MFMA B-fragments (verified qprep body) ----
  // Frag t: ((b*4 + kb)*2 + sh)*64 + lane ; elem[n=lane&15][k=kb*32+(lane>>4)*8+j]
  {
    int t = bx * 512 + tid;            // blocks 0..31 cover all 16384 frags
    if (t < 16384) {
      int l2  = t & 63;
      int sh2 = (t >> 6) & 1;
      int kb2 = (t >> 7) & 3;
      int b2  = t >> 9;
      int s2  = sh2 * 16 + (l2 & 15);
      int h2  = kb2 * 32 + (l2 >> 4) * 8;
      const float* src = q + ((b2 * 32 + s2) * H + h2);
      float4 v0 = *(const float4*)src;
      float4 v1 = *(const float4*)(src + 4);
      half8v o = { (_Float16)v0.x, (_Float16)v0.y, (_Float16)v0.z, (_Float16)v0.w,
                   (_Float16)v1.x, (_Float16)v1.y, (_Float16)v1.z, (_Float16)v1.w };
      *(half8v*)(qs + (size_t)t * 8) = o;
    }
  }
  cg::this_grid().sync();

  // ---- P1: scores.  c = 2*bx + cs ----
  {
    const half8v* qf = (const half8v*)qs;
    const float*  pc = pos + (size_t)(2 * bx + cs) * (D * H);

    half8v  pa[4][4];    // P_c A-frags [mt][kb]  (64 VGPRs)
    half8v  qb[3][4];    // Q B-frags, ring, prefetch distance 2 (48 VGPRs)
    floatx4 acc[2][4];   // [buf][mt] (32 VGPRs)
    floatx4 zc = {0.f, 0.f, 0.f, 0.f};

    // P_c A-frags: A[m = dq*64 + mt*16 + nrow][k = kb*32 + quad*8 + j]
#pragma unroll
    for (int kb = 0; kb < 4; ++kb)
#pragma unroll
      for (int mt = 0; mt < 4; ++mt) {
        const float* src = pc + ((dq * 64 + mt * 16 + nrow) * H + kb * 32 + quad * 8);
        float4 v0 = *(const float4*)src;
        float4 v1 = *(const float4*)(src + 4);
        half8v f = { (_Float16)v0.x, (_Float16)v0.y, (_Float16)v0.z, (_Float16)v0.w,
                     (_Float16)v1.x, (_Float16)v1.y, (_Float16)v1.z, (_Float16)v1.w };
        pa[mt][kb] = f;
      }

    // Q fragments for b=0,1 (prime pipeline to depth 2)
#pragma unroll
    for (int kb = 0; kb < 4; ++kb) qb[0][kb] = qf[(kb * 2 + sh) * 64 + lane];
#pragma unroll
    for (int kb = 0; kb < 4; ++kb) qb[1][kb] = qf[((4 + kb) * 2 + sh) * 64 + lane];

    // C/D: col s_local = lane&15, row d_local = quad*4 + r  [m89/m91]
    auto reduce_store = [&](int b, floatx4 (&a)[4]) {
      float m0 = fmaxf(fmaxf(a[0][0], a[0][1]), fmaxf(a[0][2], a[0][3]));
      float m1 = fmaxf(fmaxf(a[1][0], a[1][1]), fmaxf(a[1][2], a[1][3]));
      float m2 = fmaxf(fmaxf(a[2][0], a[2][1]), fmaxf(a[2][2], a[2][3]));
      float m3 = fmaxf(fmaxf(a[3][0], a[3][1]), fmaxf(a[3][2], a[3][3]));
      float m  = fmaxf(fmaxf(m0, m1), fmaxf(m2, m3));
      m = fmaxf(m, __shfl_xor(m, 16));
      m = fmaxf(m, __shfl_xor(m, 32));
      if (lane < 16) pmm[cs][b][w4][lane] = m;
    };

    // main loop: prefetch b+2, compute b, reduce b-1 (r0-identical)
#pragma unroll
    for (int b = 0; b < BQ; ++b) {
      const int cur = b & 1;
      if (b + 2 < BQ) {
        half8v* dst = qb[(b + 2) % 3];
#pragma unroll
        for (int kb = 0; kb < 4; ++kb) dst[kb] = qf[(((b + 2) * 4 + kb) * 2 + sh) * 64 + lane];
      }
      const half8v* qc = qb[b % 3];
#pragma unroll
      for (int mt = 0; mt < 4; ++mt)
        acc[cur][mt] = __builtin_amdgcn_mfma_f32_16x16x32_f16(pa[mt][0], qc[0], zc, 0, 0, 0);
#pragma unroll
      for (int kb = 1; kb < 4; ++kb)
#pragma unroll
        for (int mt = 0; mt < 4; ++mt)
          acc[cur][mt] = __builtin_amdgcn_mfma_f32_16x16x32_f16(pa[mt][kb], qc[kb], acc[cur][mt], 0, 0, 0);
      if (b > 0) reduce_store(b - 1, acc[cur ^ 1]);
    }
    reduce_store(BQ - 1, acc[1]);   // b=31 landed in acc[1]

    __syncthreads();

    // epilogue (r1-verified): scores[b][2bx+cs2] = 50 * sum_s max over d-halves
    {
      int cs2 = tid >> 8;
      int r   = tid & 255;
      int b   = r >> 3;
      int t8  = r & 7;
      float v = 0.f;
#pragma unroll
      for (int j = 0; j < 4; ++j) {
        int s  = t8 * 4 + j;
        int h2 = s >> 4, sl = s & 15;
        v += fmaxf(pmm[cs2][b][2 * h2][sl], pmm[cs2][b][2 * h2 + 1][sl]);
      }
      v += __shfl_xor(v, 1);
      v += __shfl_xor(v, 2);
      v += __shfl_xor(v, 4);
      if (t8 == 0) scores[b * C + (2 * bx + cs2)] = v * 50.0f;   // / TEMPERATURE
    }
  }
  cg::this_grid().sync();

  // ---- P2: loss on block 0 (r2-verified 512-thread body) ----
  if (bx == 0) {
    float part = 0.f;
#pragma unroll
    for (int i = 0; i < 4; ++i) {
      const int b = w * 4 + i;
      const float* row = scores + b * C;
      const float4* r4 = (const float4*)row;
      float4 v0 = r4[lane * 2];
      float4 v1 = r4[lane * 2 + 1];
      float mx = fmaxf(fmaxf(fmaxf(v0.x, v0.y), fmaxf(v0.z, v0.w)),
                       fmaxf(fmaxf(v1.x, v1.y), fmaxf(v1.z, v1.w)));
#pragma unroll
      for (int off = 1; off < 64; off <<= 1) mx = fmaxf(mx, __shfl_xor(mx, off));
      float e = __expf(v0.x - mx) + __expf(v0.y - mx) + __expf(v0.z - mx) + __expf(v0.w - mx)
              + __expf(v1.x - mx) + __expf(v1.y - mx) + __expf(v1.z - mx) + __expf(v1.w - mx);
#pragma unroll
      for (int off = 1; off < 64; off <<= 1) e += __shfl_xor(e, off);
      if (lane == 0) part += mx + __logf(e) - row[0];
    }
    if (lane == 0) red[w] = part;
    __syncthreads();
    if (tid == 0) {
      float s = red[0] + red[1] + red[2] + red[3] + red[4] + red[5] + red[6] + red[7];
      out[0] = s * (1.0f / 32.0f);
    }
  }
}

extern "C" void kernel_launch(void* const* d_in, const int* in_sizes, int n_in,
                              void* d_out, int out_size, void* d_ws, size_t ws_size,
                              hipStream_t stream) {
  const float* q = (const float*)d_in[0];   // [32,32,128] fp32
  const float* p = (const float*)d_in[1];   // [512,128,128] fp32
  float* scores  = (float*)d_ws;                              // 64 KB
  _Float16* qs   = (_Float16*)((char*)d_ws + 65536);          // 256 KB fp16 frags
  float* outp    = (float*)d_out;

  void* args[] = { (void*)&p, (void*)&q, (void*)&scores, (void*)&qs, (void*)&outp };
  hipLaunchCooperativeKernel((void*)mono_kernel, dim3(256), dim3(512), args, 0, stream);
}

// Round 4
// 160.832 us; speedup vs baseline: 1.0088x; 1.0088x over previous
//
#include <hip/hip_runtime.h>

#define BQ 32
#define H  128
#define C  512
#define D  128

typedef _Float16 half8v __attribute__((ext_vector_type(8)));
typedef float floatx4 __attribute__((ext_vector_type(4)));

#define FLAG_V   0x13579BDFu
#define FLAG_MAG 0xDEADBEEFu

__device__ __forceinline__ half8v cvt2(float4 a, float4 b) {
  half8v f = { (_Float16)a.x, (_Float16)a.y, (_Float16)a.z, (_Float16)a.w,
               (_Float16)b.x, (_Float16)b.y, (_Float16)b.z, (_Float16)b.w };
  return f;
}

// Inline-asm global loads: the compiler cannot sink/rematerialize these (r2:
// plain fp32 loads were sunk to their uses, VGPR=96, pipeline dead; r3: fused
// context broke the fp16 ring the same way).  Two insts share one address.
#define GLOAD2(d0, d1, p) \
  asm volatile("global_load_dwordx4 %0, %2, off\n\t" \
               "global_load_dwordx4 %1, %2, off offset:16" \
               : "=v"(d0), "=v"(d1) : "v"(p))

// Issue one Q slab (b) = 8 float4 per lane into register set SET.
#define ISSUE8(SET, bb) do { \
  const float* _p = qsrc + (bb) * (BQ * H); \
  GLOAD2(SET[0], SET[1], _p); \
  GLOAD2(SET[2], SET[3], _p + 32); \
  GLOAD2(SET[4], SET[5], _p + 64); \
  GLOAD2(SET[6], SET[7], _p + 96); \
} while (0)

// Counted wait + scheduler fence (rule 18: VALU/MFMA hoist past asm waitcnt
// unless pinned with sched_barrier).
#define VWAITN(N) do { \
  asm volatile("s_waitcnt vmcnt(" #N ")" ::: "memory"); \
  __builtin_amdgcn_sched_barrier(0); \
} while (0)

// One b-iteration.  vmcnt(8): with slabs b,b+1 in flight (16 ops) this
// completes the 8 OLDEST = slab b (m135 oldest-N semantics).  cvts are
// fenced between the wait and the reissue (reissue overwrites SET).
#define SCORE_ITER(B, SET, N, DOISSUE) do { \
  VWAITN(N); \
  half8v qc0 = cvt2(SET[0], SET[1]); \
  half8v qc1 = cvt2(SET[2], SET[3]); \
  half8v qc2 = cvt2(SET[4], SET[5]); \
  half8v qc3 = cvt2(SET[6], SET[7]); \
  __builtin_amdgcn_sched_barrier(0); \
  DOISSUE; \
  acc[(B)&1][0] = __builtin_amdgcn_mfma_f32_16x16x32_f16(pa[0][0], qc0, zc, 0, 0, 0); \
  acc[(B)&1][1] = __builtin_amdgcn_mfma_f32_16x16x32_f16(pa[1][0], qc0, zc, 0, 0, 0); \
  acc[(B)&1][2] = __builtin_amdgcn_mfma_f32_16x16x32_f16(pa[2][0], qc0, zc, 0, 0, 0); \
  acc[(B)&1][3] = __builtin_amdgcn_mfma_f32_16x16x32_f16(pa[3][0], qc0, zc, 0, 0, 0); \
  acc[(B)&1][0] = __builtin_amdgcn_mfma_f32_16x16x32_f16(pa[0][1], qc1, acc[(B)&1][0], 0, 0, 0); \
  acc[(B)&1][1] = __builtin_amdgcn_mfma_f32_16x16x32_f16(pa[1][1], qc1, acc[(B)&1][1], 0, 0, 0); \
  acc[(B)&1][2] = __builtin_amdgcn_mfma_f32_16x16x32_f16(pa[2][1], qc1, acc[(B)&1][2], 0, 0, 0); \
  acc[(B)&1][3] = __builtin_amdgcn_mfma_f32_16x16x32_f16(pa[3][1], qc1, acc[(B)&1][3], 0, 0, 0); \
  acc[(B)&1][0] = __builtin_amdgcn_mfma_f32_16x16x32_f16(pa[0][2], qc2, acc[(B)&1][0], 0, 0, 0); \
  acc[(B)&1][1] = __builtin_amdgcn_mfma_f32_16x16x32_f16(pa[1][2], qc2, acc[(B)&1][1], 0, 0, 0); \
  acc[(B)&1][2] = __builtin_amdgcn_mfma_f32_16x16x32_f16(pa[2][2], qc2, acc[(B)&1][2], 0, 0, 0); \
  acc[(B)&1][3] = __builtin_amdgcn_mfma_f32_16x16x32_f16(pa[3][2], qc2, acc[(B)&1][3], 0, 0, 0); \
  acc[(B)&1][0] = __builtin_amdgcn_mfma_f32_16x16x32_f16(pa[0][3], qc3, acc[(B)&1][0], 0, 0, 0); \
  acc[(B)&1][1] = __builtin_amdgcn_mfma_f32_16x16x32_f16(pa[1][3], qc3, acc[(B)&1][1], 0, 0, 0); \
  acc[(B)&1][2] = __builtin_amdgcn_mfma_f32_16x16x32_f16(pa[2][3], qc3, acc[(B)&1][2], 0, 0, 0); \
  acc[(B)&1][3] = __builtin_amdgcn_mfma_f32_16x16x32_f16(pa[3][3], qc3, acc[(B)&1][3], 0, 0, 0); \
  if ((B) > 0) reduce_store((B)-1, acc[((B)&1)^1]); \
} while (0)

// ---------------------------------------------------------------------------
// Single regular launch, grid 513 x 256.
// Blocks 0..511: r0's verified scores body (4 waves, P-stationary, register Q)
//   with the Q pipeline pinned by inline asm (fp32 direct, cvt at use).
// Block 512: spin-waits on init-free flag pairs, then computes the loss.
//   Poison fill (P,P) never satisfies f0^f1==MAGIC, so the harness's own
//   re-poison resets the flags; producers never wait => no deadlock.
// ---------------------------------------------------------------------------
__global__ __launch_bounds__(256, 2) void fused_kernel(const float* __restrict__ pos,
                                                       const float* __restrict__ q,
                                                       float* __restrict__ scores,
                                                       unsigned int* __restrict__ flags,
                                                       float* __restrict__ out) {
  const int tid  = threadIdx.x;
  const int w    = tid >> 6;
  const int lane = tid & 63;

  __shared__ float pmm[BQ][4][16];   // 8 KB (loss block reuses as red[])

  if (blockIdx.x < C) {
    // ================= scores block =================
    const int c    = blockIdx.x;
    const int dq   = w & 1;          // d-half
    const int sh   = w >> 1;         // s-half
    const int quad = lane >> 4;
    const int nrow = lane & 15;

    // Per-lane Q source base; slab b is +b*4096 floats.
    const float* qsrc = q + ((sh * 16 + nrow) * H + quad * 8);

    float4 qA[8], qB[8];             // two slab register sets (64 VGPRs)
    ISSUE8(qA, 0);                   // slab 0
    ISSUE8(qB, 1);                   // slab 1

    // P_c A-frags: A[m = dq*64 + mt*16 + nrow][k = kb*32 + quad*8 + j]
    const float* pc = pos + (size_t)c * (D * H);
    half8v pa[4][4];                 // 64 VGPRs
#pragma unroll
    for (int kb = 0; kb < 4; ++kb)
#pragma unroll
      for (int mt = 0; mt < 4; ++mt) {
        const float* src = pc + ((dq * 64 + mt * 16 + nrow) * H + kb * 32 + quad * 8);
        float4 v0 = *(const float4*)src;
        float4 v1 = *(const float4*)(src + 4);
        pa[mt][kb] = cvt2(v0, v1);
      }

    floatx4 acc[2][4];
    floatx4 zc = {0.f, 0.f, 0.f, 0.f};

    // C/D: col s_local = lane&15, row d_local = quad*4 + r  [m89/m91]
    auto reduce_store = [&](int b, floatx4 (&a)[4]) {
      float m0 = fmaxf(fmaxf(a[0][0], a[0][1]), fmaxf(a[0][2], a[0][3]));
      float m1 = fmaxf(fmaxf(a[1][0], a[1][1]), fmaxf(a[1][2], a[1][3]));
      float m2 = fmaxf(fmaxf(a[2][0], a[2][1]), fmaxf(a[2][2], a[2][3]));
      float m3 = fmaxf(fmaxf(a[3][0], a[3][1]), fmaxf(a[3][2], a[3][3]));
      float m  = fmaxf(fmaxf(m0, m1), fmaxf(m2, m3));
      m = fmaxf(m, __shfl_xor(m, 16));
      m = fmaxf(m, __shfl_xor(m, 32));
      if (lane < 16) pmm[b][w][lane] = m;
    };

    SCORE_ITER( 0, qA, 8, ISSUE8(qA,  2));
    SCORE_ITER( 1, qB, 8, ISSUE8(qB,  3));
    SCORE_ITER( 2, qA, 8, ISSUE8(qA,  4));
    SCORE_ITER( 3, qB, 8, ISSUE8(qB,  5));
    SCORE_ITER( 4, qA, 8, ISSUE8(qA,  6));
    SCORE_ITER( 5, qB, 8, ISSUE8(qB,  7));
    SCORE_ITER( 6, qA, 8, ISSUE8(qA,  8));
    SCORE_ITER( 7, qB, 8, ISSUE8(qB,  9));
    SCORE_ITER( 8, qA, 8, ISSUE8(qA, 10));
    SCORE_ITER( 9, qB, 8, ISSUE8(qB, 11));
    SCORE_ITER(10, qA, 8, ISSUE8(qA, 12));
    SCORE_ITER(11, qB, 8, ISSUE8(qB, 13));
    SCORE_ITER(12, qA, 8, ISSUE8(qA, 14));
    SCORE_ITER(13, qB, 8, ISSUE8(qB, 15));
    SCORE_ITER(14, qA, 8, ISSUE8(qA, 16));
    SCORE_ITER(15, qB, 8, ISSUE8(qB, 17));
    SCORE_ITER(16, qA, 8, ISSUE8(qA, 18));
    SCORE_ITER(17, qB, 8, ISSUE8(qB, 19));
    SCORE_ITER(18, qA, 8, ISSUE8(qA, 20));
    SCORE_ITER(19, qB, 8, ISSUE8(qB, 21));
    SCORE_ITER(20, qA, 8, ISSUE8(qA, 22));
    SCORE_ITER(21, qB, 8, ISSUE8(qB, 23));
    SCORE_ITER(22, qA, 8, ISSUE8(qA, 24));
    SCORE_ITER(23, qB, 8, ISSUE8(qB, 25));
    SCORE_ITER(24, qA, 8, ISSUE8(qA, 26));
    SCORE_ITER(25, qB, 8, ISSUE8(qB, 27));
    SCORE_ITER(26, qA, 8, ISSUE8(qA, 28));
    SCORE_ITER(27, qB, 8, ISSUE8(qB, 29));
    SCORE_ITER(28, qA, 8, ISSUE8(qA, 30));
    SCORE_ITER(29, qB, 8, ISSUE8(qB, 31));
    SCORE_ITER(30, qA, 8, (void)0);      // slab30 done when <=8 outstanding
    SCORE_ITER(31, qB, 0, (void)0);      // drain slab31
    reduce_store(BQ - 1, acc[1]);        // b=31 landed in acc[1]

    __syncthreads();

    // epilogue: scores[b][c] = 50 * sum_s max over the two d-half waves
    {
      int b  = tid >> 3;
      int t8 = tid & 7;
      float v = 0.f;
#pragma unroll
      for (int j = 0; j < 4; ++j) {
        int s  = t8 * 4 + j;
        int h2 = s >> 4, sl = s & 15;
        v += fmaxf(pmm[b][2 * h2][sl], pmm[b][2 * h2 + 1][sl]);
      }
      v += __shfl_xor(v, 1);
      v += __shfl_xor(v, 2);
      v += __shfl_xor(v, 4);
      if (t8 == 0) scores[b * C + c] = v * 50.0f;   // / TEMPERATURE
    }

    // publish: all 32 score stores drained by __syncthreads (vmcnt(0)),
    // then device-scope fence (flushes the shared per-XCD L2) + flag pair.
    __syncthreads();
    if (tid == 0) {
      __threadfence();
      __hip_atomic_store(flags + 2 * c,     FLAG_V,            __ATOMIC_RELEASE, __HIP_MEMORY_SCOPE_AGENT);
      __hip_atomic_store(flags + 2 * c + 1, FLAG_V ^ FLAG_MAG, __ATOMIC_RELEASE, __HIP_MEMORY_SCOPE_AGENT);
    }
  } else {
    // ================= loss block (spin consumer) =================
    const int c0 = tid * 2;          // each thread owns flags for c0, c0+1
    unsigned int f0, f1;
    do {
      f0 = __hip_atomic_load(flags + 2 * c0,     __ATOMIC_RELAXED, __HIP_MEMORY_SCOPE_AGENT);
      f1 = __hip_atomic_load(flags + 2 * c0 + 1, __ATOMIC_RELAXED, __HIP_MEMORY_SCOPE_AGENT);
      if ((f0 ^ f1) != FLAG_MAG) __builtin_amdgcn_s_sleep(2);
    } while ((f0 ^ f1) != FLAG_MAG);
    do {
      f0 = __hip_atomic_load(flags + 2 * c0 + 2, __ATOMIC_RELAXED, __HIP_MEMORY_SCOPE_AGENT);
      f1 = __hip_atomic_load(flags + 2 * c0 + 3, __ATOMIC_RELAXED, __HIP_MEMORY_SCOPE_AGENT);
      if ((f0 ^ f1) != FLAG_MAG) __builtin_amdgcn_s_sleep(2);
    } while ((f0 ^ f1) != FLAG_MAG);
    __syncthreads();
    __threadfence();                 // acquire: invalidate L1/L2 before reads

    // r2-verified loss math, bit-identical order: 4 waves x 2 virtual passes
    float* red = (float*)pmm;
    float part0 = 0.f, part1 = 0.f;
#pragma unroll
    for (int half = 0; half < 2; ++half)
#pragma unroll
      for (int i = 0; i < 4; ++i) {
        const int b = (w + half * 4) * 4 + i;
        const float* row = scores + b * C;
        const float4* r4 = (const float4*)row;
        float4 v0 = r4[lane * 2];
        float4 v1 = r4[lane * 2 + 1];
        float mx = fmaxf(fmaxf(fmaxf(v0.x, v0.y), fmaxf(v0.z, v0.w)),
                         fmaxf(fmaxf(v1.x, v1.y), fmaxf(v1.z, v1.w)));
#pragma unroll
        for (int off = 1; off < 64; off <<= 1) mx = fmaxf(mx, __shfl_xor(mx, off));
        float e = __expf(v0.x - mx) + __expf(v0.y - mx) + __expf(v0.z - mx) + __expf(v0.w - mx)
                + __expf(v1.x - mx) + __expf(v1.y - mx) + __expf(v1.z - mx) + __expf(v1.w - mx);
#pragma unroll
        for (int off = 1; off < 64; off <<= 1) e += __shfl_xor(e, off);
        if (lane == 0) {
          float t = mx + __logf(e) - row[0];
          if (half == 0) part0 += t; else part1 += t;
        }
      }
    if (lane == 0) { red[w] = part0; red[w + 4] = part1; }
    __syncthreads();
    if (tid == 0) {
      float s = red[0] + red[1] + red[2] + red[3] + red[4] + red[5] + red[6] + red[7];
      out[0] = s * (1.0f / 32.0f);
    }
  }
}

extern "C" void kernel_launch(void* const* d_in, const int* in_sizes, int n_in,
                              void* d_out, int out_size, void* d_ws, size_t ws_size,
                              hipStream_t stream) {
  const float* q = (const float*)d_in[0];   // [32,32,128] fp32
  const float* p = (const float*)d_in[1];   // [512,128,128] fp32
  float* scores  = (float*)d_ws;                              // 64 KB
  unsigned int* flags = (unsigned int*)((char*)d_ws + 65536); // 4 KB, poison-reset

  fused_kernel<<<C + 1, 256, 0, stream>>>(p, q, scores, flags, (float*)d_out);
}

// Round 6
// 99.360 us; speedup vs baseline: 1.6329x; 1.6187x over previous
//
#include <hip/hip_runtime.h>

#define BQ 32
#define H  128
#define C  512
#define D  128

typedef _Float16 half8v __attribute__((ext_vector_type(8)));
typedef float floatx4 __attribute__((ext_vector_type(4)));

// ---------------------------------------------------------------------------
// Kernel 0: Q fp32 -> fp16 fragments for 16x16x32 MFMA B-operand, plus zero
// the loss accumulator (d_out).  BYTE-IDENTICAL to the 93.8us baseline.
// Frag index (half8 units): ((b*4 + kb)*2 + sh)*64 + lane
//   elem[n = lane&15][k = kb*32 + (lane>>4)*8 + j],  s = sh*16 + n
// ---------------------------------------------------------------------------
__global__ __launch_bounds__(256) void qprep_kernel(const float* __restrict__ q,
                                                    _Float16* __restrict__ qs,
                                                    float* __restrict__ out) {
  int t = blockIdx.x * 256 + threadIdx.x;     // 0..16383, one half8 frag each
  if (t == 0) out[0] = 0.0f;
  int lane = t & 63;
  int sh   = (t >> 6) & 1;
  int kb   = (t >> 7) & 3;
  int b    = t >> 9;
  int s    = sh * 16 + (lane & 15);
  int h    = kb * 32 + (lane >> 4) * 8;
  const float* src = q + ((b * 32 + s) * H + h);
  float4 v0 = *(const float4*)src;
  float4 v1 = *(const float4*)(src + 4);
  half8v o = { (_Float16)v0.x, (_Float16)v0.y, (_Float16)v0.z, (_Float16)v0.w,
               (_Float16)v1.x, (_Float16)v1.y, (_Float16)v1.z, (_Float16)v1.w };
  *(half8v*)(qs + (size_t)t * 8) = o;
}

// ---------------------------------------------------------------------------
// Kernel 1: block c (512 thr, 8 waves) -> scores[b][c].
// SINGLE CHANGE vs the 93.8us baseline: 8 waves/block, each wave owns a
// d-QUARTER (32 rows, 2 m-tiles) instead of a d-half.  Rationale (r2/r4
// accounting): scores ran ~26us at 2 waves/SIMD, latency-bound on the
// distance-2 Q ring (L2 ~200cyc vs ~160cyc slack).  Per-wave VGPR drops to
// pa 32 + qb 48 + acc 16 ~= 110 <= 128 cap, so __launch_bounds__(512,4)
// holds 4 waves/SIMD -- double the TLP, same proven ring/prefetch codegen
// (strictly LOWER register pressure than the baseline body, unlike the
// r2/r3/r4 restructures that collapsed).
// Wave w: d-quarter dqt=w&3 (rows dqt*32..+31), s-half sh=w>>2.
// ---------------------------------------------------------------------------
__global__ __launch_bounds__(512, 4) void scores_kernel(const float* __restrict__ pos,
                                                        const _Float16* __restrict__ qs,
                                                        float* __restrict__ scores) {
  const int c    = blockIdx.x;
  const int tid  = threadIdx.x;
  const int w    = tid >> 6;         // 0..7
  const int lane = tid & 63;
  const int dqt  = w & 3;            // d-quarter
  const int sh   = w >> 2;           // s-half
  const int quad = lane >> 4;
  const int nrow = lane & 15;

  __shared__ float pmm[BQ][8][16];   // [b][wave][s_local]  16 KB

  const half8v* qf = (const half8v*)qs;
  const float*  pc = pos + (size_t)c * (D * H);

  half8v  pa[2][4];    // P_c A-frags [mt][kb]  (32 VGPRs)
  half8v  qb[3][4];    // Q B-frags, round-robin, prefetch distance 2 (48 VGPRs)
  floatx4 acc[2][2];   // [buf][mt] (16 VGPRs)
  floatx4 zc = {0.f, 0.f, 0.f, 0.f};

  // P_c A-frags: A[m = dqt*32 + mt*16 + nrow][k = kb*32 + quad*8 + j]
#pragma unroll
  for (int kb = 0; kb < 4; ++kb)
#pragma unroll
    for (int mt = 0; mt < 2; ++mt) {
      const float* src = pc + ((dqt * 32 + mt * 16 + nrow) * H + kb * 32 + quad * 8);
      float4 v0 = *(const float4*)src;
      float4 v1 = *(const float4*)(src + 4);
      half8v f = { (_Float16)v0.x, (_Float16)v0.y, (_Float16)v0.z, (_Float16)v0.w,
                   (_Float16)v1.x, (_Float16)v1.y, (_Float16)v1.z, (_Float16)v1.w };
      pa[mt][kb] = f;
    }

  // Q fragments for b=0,1 (prefetch pipeline primed to depth 2)
#pragma unroll
  for (int kb = 0; kb < 4; ++kb) qb[0][kb] = qf[(kb * 2 + sh) * 64 + lane];
#pragma unroll
  for (int kb = 0; kb < 4; ++kb) qb[1][kb] = qf[((4 + kb) * 2 + sh) * 64 + lane];

  // Reduce: max over this wave's 32 d-rows for each of its 16 s.
  // C/D: col s_local = lane&15, row d_local = quad*4 + r  [m89/m91]
  auto reduce_store = [&](int b, floatx4 (&a)[2]) {
    float m0 = fmaxf(fmaxf(a[0][0], a[0][1]), fmaxf(a[0][2], a[0][3]));
    float m1 = fmaxf(fmaxf(a[1][0], a[1][1]), fmaxf(a[1][2], a[1][3]));
    float m  = fmaxf(m0, m1);
    m = fmaxf(m, __shfl_xor(m, 16));
    m = fmaxf(m, __shfl_xor(m, 32));
    if (lane < 16) pmm[b][w][lane] = m;
  };

  // main loop: prefetch b+2 (distance 2), compute b, reduce b-1
#pragma unroll
  for (int b = 0; b < BQ; ++b) {
    const int cur = b & 1;
    if (b + 2 < BQ) {
      half8v* dst = qb[(b + 2) % 3];
#pragma unroll
      for (int kb = 0; kb < 4; ++kb) dst[kb] = qf[(((b + 2) * 4 + kb) * 2 + sh) * 64 + lane];
    }
    const half8v* qc = qb[b % 3];
#pragma unroll
    for (int mt = 0; mt < 2; ++mt)
      acc[cur][mt] = __builtin_amdgcn_mfma_f32_16x16x32_f16(pa[mt][0], qc[0], zc, 0, 0, 0);
#pragma unroll
    for (int kb = 1; kb < 4; ++kb)
#pragma unroll
      for (int mt = 0; mt < 2; ++mt)
        acc[cur][mt] = __builtin_amdgcn_mfma_f32_16x16x32_f16(pa[mt][kb], qc[kb], acc[cur][mt], 0, 0, 0);
    if (b > 0) reduce_store(b - 1, acc[cur ^ 1]);
  }
  reduce_store(BQ - 1, acc[1]);   // b=31 landed in acc[1]

  __syncthreads();

  // epilogue (first 4 waves): scores[b][c] = 50 * sum_s max over 4 d-quarters
  if (tid < 256) {
    int b  = tid >> 3;
    int t8 = tid & 7;
    float v = 0.f;
#pragma unroll
    for (int j = 0; j < 4; ++j) {
      int s  = t8 * 4 + j;
      int h2 = s >> 4, sl = s & 15;   // wave for (sh=h2, dqt=k) is h2*4+k
      v += fmaxf(fmaxf(pmm[b][h2 * 4 + 0][sl], pmm[b][h2 * 4 + 1][sl]),
                 fmaxf(pmm[b][h2 * 4 + 2][sl], pmm[b][h2 * 4 + 3][sl]));
    }
    v += __shfl_xor(v, 1);
    v += __shfl_xor(v, 2);
    v += __shfl_xor(v, 4);
    if (t8 == 0) scores[b * C + c] = v * 50.0f;   // / TEMPERATURE
  }
}

// ---------------------------------------------------------------------------
// Kernel 2: one block per b; loss += (logsumexp_c - scores[b][0]) / 32
// BYTE-IDENTICAL to the 93.8us baseline.
// ---------------------------------------------------------------------------
__global__ __launch_bounds__(256) void loss_kernel(const float* __restrict__ scores,
                                                   float* __restrict__ out) {
  __shared__ float red[8];
  const int b = blockIdx.x, tid = threadIdx.x, w = tid >> 6, lane = tid & 63;
  const float* row = scores + b * C;
  float x0 = row[tid], x1 = row[tid + 256];
  float mx = fmaxf(x0, x1);
#pragma unroll
  for (int off = 1; off < 64; off <<= 1) mx = fmaxf(mx, __shfl_xor(mx, off));
  if (lane == 0) red[w] = mx;
  __syncthreads();
  float bmax = fmaxf(fmaxf(red[0], red[1]), fmaxf(red[2], red[3]));
  float e = __expf(x0 - bmax) + __expf(x1 - bmax);
#pragma unroll
  for (int off = 1; off < 64; off <<= 1) e += __shfl_xor(e, off);
  if (lane == 0) red[4 + w] = e;
  __syncthreads();
  if (tid == 0) {
    float s = red[4] + red[5] + red[6] + red[7];
    atomicAdd(out, (bmax + __logf(s) - row[0]) * (1.0f / 32.0f));
  }
}

extern "C" void kernel_launch(void* const* d_in, const int* in_sizes, int n_in,
                              void* d_out, int out_size, void* d_ws, size_t ws_size,
                              hipStream_t stream) {
  const float* q = (const float*)d_in[0];   // [32,32,128] fp32
  const float* p = (const float*)d_in[1];   // [512,128,128] fp32
  float* scores  = (float*)d_ws;                              // 64 KB
  _Float16* qs   = (_Float16*)((char*)d_ws + 65536);          // 256 KB fp16 frags

  qprep_kernel<<<64, 256, 0, stream>>>(q, qs, (float*)d_out);
  scores_kernel<<<C, 512, 0, stream>>>(p, qs, scores);
  loss_kernel<<<32, 256, 0, stream>>>(scores, (float*)d_out);
}

// Round 7
// 98.247 us; speedup vs baseline: 1.6514x; 1.0113x over previous
//
#include <hip/hip_runtime.h>

#define BQ 32
#define H  128
#define C  512
#define D  128

typedef _Float16 half8v __attribute__((ext_vector_type(8)));
typedef float floatx4 __attribute__((ext_vector_type(4)));

// ---------------------------------------------------------------------------
// Kernel 0: Q fp32 -> fp16 fragments (BYTE-IDENTICAL to the 93.8us baseline).
// Frag index (half8 units): ((b*4 + kb)*2 + sh)*64 + lane
// ---------------------------------------------------------------------------
__global__ __launch_bounds__(256) void qprep_kernel(const float* __restrict__ q,
                                                    _Float16* __restrict__ qs,
                                                    float* __restrict__ out) {
  int t = blockIdx.x * 256 + threadIdx.x;
  if (t == 0) out[0] = 0.0f;
  int lane = t & 63;
  int sh   = (t >> 6) & 1;
  int kb   = (t >> 7) & 3;
  int b    = t >> 9;
  int s    = sh * 16 + (lane & 15);
  int h    = kb * 32 + (lane >> 4) * 8;
  const float* src = q + ((b * 32 + s) * H + h);
  float4 v0 = *(const float4*)src;
  float4 v1 = *(const float4*)(src + 4);
  half8v o = { (_Float16)v0.x, (_Float16)v0.y, (_Float16)v0.z, (_Float16)v0.w,
               (_Float16)v1.x, (_Float16)v1.y, (_Float16)v1.z, (_Float16)v1.w };
  *(half8v*)(qs + (size_t)t * 8) = o;
}

// ---------------------------------------------------------------------------
// Kernel 1: block = c-PAIR (256 thr, 4 waves) -> scores[b][2bx], scores[b][2bx+1].
// Theory (r0/r6 counter fit): kernel is Q-operand-bandwidth-bound.  MFMA rate
// ~4.85cyc/CU; Q demand = 211/R B/cyc/CU where R = MFMAs per Q-frag read.
// r0: R=4 -> 53 B/cyc ~= L2 ceiling (56).  r6: R=2 -> 2x over (regressed).
// HERE: R=8 -- each wave holds P A-frags for BOTH c's of the pair and issues
// 32 MFMA per Q-frag set.  Q demand 26 B/cyc/CU, well under L2.
// Wave role (dq = w&1, sh = w>>1) and ALL fragment math identical to r0.
// No acc double-buffer (reduce at iter end) to stay under the 256-VGPR cap:
// pa 128 + qb 48 + acc 32 + temps ~= 225.
// ---------------------------------------------------------------------------
__global__ __launch_bounds__(256, 2) void scores_kernel(const float* __restrict__ pos,
                                                        const _Float16* __restrict__ qs,
                                                        float* __restrict__ scores) {
  const int bx   = blockIdx.x;
  const int tid  = threadIdx.x;
  const int w    = tid >> 6;
  const int lane = tid & 63;
  const int dq   = w & 1;            // d-half
  const int sh   = w >> 1;           // s-half
  const int quad = lane >> 4;
  const int nrow = lane & 15;

  __shared__ float pmm[2][BQ][4][16];   // [cs][b][wave][s_local]  16 KB

  const half8v* qf = (const half8v*)qs;

  half8v qb[3][4];     // Q ring, prefetch distance 2 (48 VGPRs) -- r0-identical
#pragma unroll
  for (int kb = 0; kb < 4; ++kb) qb[0][kb] = qf[(kb * 2 + sh) * 64 + lane];
#pragma unroll
  for (int kb = 0; kb < 4; ++kb) qb[1][kb] = qf[((4 + kb) * 2 + sh) * 64 + lane];

  // P A-frags for BOTH c's: A[m = dq*64 + mt*16 + nrow][k = kb*32 + quad*8 + j]
  const float* pc0 = pos + (size_t)(2 * bx)     * (D * H);
  const float* pc1 = pos + (size_t)(2 * bx + 1) * (D * H);
  half8v pa0[4][4], pa1[4][4];       // 128 VGPRs
#pragma unroll
  for (int kb = 0; kb < 4; ++kb)
#pragma unroll
    for (int mt = 0; mt < 4; ++mt) {
      const int off = (dq * 64 + mt * 16 + nrow) * H + kb * 32 + quad * 8;
      float4 a0 = *(const float4*)(pc0 + off);
      float4 a1 = *(const float4*)(pc0 + off + 4);
      half8v f0 = { (_Float16)a0.x, (_Float16)a0.y, (_Float16)a0.z, (_Float16)a0.w,
                    (_Float16)a1.x, (_Float16)a1.y, (_Float16)a1.z, (_Float16)a1.w };
      pa0[mt][kb] = f0;
      float4 b0 = *(const float4*)(pc1 + off);
      float4 b1 = *(const float4*)(pc1 + off + 4);
      half8v f1 = { (_Float16)b0.x, (_Float16)b0.y, (_Float16)b0.z, (_Float16)b0.w,
                    (_Float16)b1.x, (_Float16)b1.y, (_Float16)b1.z, (_Float16)b1.w };
      pa1[mt][kb] = f1;
    }

  floatx4 acc0[4], acc1[4];          // 32 VGPRs (single-buffered)
  floatx4 zc = {0.f, 0.f, 0.f, 0.f};

  // C/D: col s_local = lane&15, row d_local = quad*4 + r  [m89/m91]
  auto reduce_store = [&](int cs, int b, floatx4 (&a)[4]) {
    float m0 = fmaxf(fmaxf(a[0][0], a[0][1]), fmaxf(a[0][2], a[0][3]));
    float m1 = fmaxf(fmaxf(a[1][0], a[1][1]), fmaxf(a[1][2], a[1][3]));
    float m2 = fmaxf(fmaxf(a[2][0], a[2][1]), fmaxf(a[2][2], a[2][3]));
    float m3 = fmaxf(fmaxf(a[3][0], a[3][1]), fmaxf(a[3][2], a[3][3]));
    float m  = fmaxf(fmaxf(m0, m1), fmaxf(m2, m3));
    m = fmaxf(m, __shfl_xor(m, 16));
    m = fmaxf(m, __shfl_xor(m, 32));
    if (lane < 16) pmm[cs][b][w][lane] = m;
  };

  // main loop: prefetch b+2, 32 MFMA on (pa0|pa1, qc), reduce both c's
#pragma unroll
  for (int b = 0; b < BQ; ++b) {
    if (b + 2 < BQ) {
      half8v* dst = qb[(b + 2) % 3];
#pragma unroll
      for (int kb = 0; kb < 4; ++kb) dst[kb] = qf[(((b + 2) * 4 + kb) * 2 + sh) * 64 + lane];
    }
    const half8v* qc = qb[b % 3];
#pragma unroll
    for (int mt = 0; mt < 4; ++mt) {
      acc0[mt] = __builtin_amdgcn_mfma_f32_16x16x32_f16(pa0[mt][0], qc[0], zc, 0, 0, 0);
      acc1[mt] = __builtin_amdgcn_mfma_f32_16x16x32_f16(pa1[mt][0], qc[0], zc, 0, 0, 0);
    }
#pragma unroll
    for (int kb = 1; kb < 4; ++kb)
#pragma unroll
      for (int mt = 0; mt < 4; ++mt) {
        acc0[mt] = __builtin_amdgcn_mfma_f32_16x16x32_f16(pa0[mt][kb], qc[kb], acc0[mt], 0, 0, 0);
        acc1[mt] = __builtin_amdgcn_mfma_f32_16x16x32_f16(pa1[mt][kb], qc[kb], acc1[mt], 0, 0, 0);
      }
    reduce_store(0, b, acc0);
    reduce_store(1, b, acc1);
  }

  __syncthreads();

  // epilogue (r0 math, looped over the pair): scores[b][2bx+cs]
#pragma unroll
  for (int cs = 0; cs < 2; ++cs) {
    int b  = tid >> 3;
    int t8 = tid & 7;
    float v = 0.f;
#pragma unroll
    for (int j = 0; j < 4; ++j) {
      int s  = t8 * 4 + j;
      int h2 = s >> 4, sl = s & 15;
      v += fmaxf(pmm[cs][b][2 * h2][sl], pmm[cs][b][2 * h2 + 1][sl]);
    }
    v += __shfl_xor(v, 1);
    v += __shfl_xor(v, 2);
    v += __shfl_xor(v, 4);
    if (t8 == 0) scores[b * C + (2 * bx + cs)] = v * 50.0f;   // / TEMPERATURE
  }
}

// ---------------------------------------------------------------------------
// Kernel 2: one block per b; loss += (logsumexp_c - scores[b][0]) / 32
// BYTE-IDENTICAL to the 93.8us baseline.
// ---------------------------------------------------------------------------
__global__ __launch_bounds__(256) void loss_kernel(const float* __restrict__ scores,
                                                   float* __restrict__ out) {
  __shared__ float red[8];
  const int b = blockIdx.x, tid = threadIdx.x, w = tid >> 6, lane = tid & 63;
  const float* row = scores + b * C;
  float x0 = row[tid], x1 = row[tid + 256];
  float mx = fmaxf(x0, x1);
#pragma unroll
  for (int off = 1; off < 64; off <<= 1) mx = fmaxf(mx, __shfl_xor(mx, off));
  if (lane == 0) red[w] = mx;
  __syncthreads();
  float bmax = fmaxf(fmaxf(red[0], red[1]), fmaxf(red[2], red[3]));
  float e = __expf(x0 - bmax) + __expf(x1 - bmax);
#pragma unroll
  for (int off = 1; off < 64; off <<= 1) e += __shfl_xor(e, off);
  if (lane == 0) red[4 + w] = e;
  __syncthreads();
  if (tid == 0) {
    float s = red[4] + red[5] + red[6] + red[7];
    atomicAdd(out, (bmax + __logf(s) - row[0]) * (1.0f / 32.0f));
  }
}

extern "C" void kernel_launch(void* const* d_in, const int* in_sizes, int n_in,
                              void* d_out, int out_size, void* d_ws, size_t ws_size,
                              hipStream_t stream) {
  const float* q = (const float*)d_in[0];   // [32,32,128] fp32
  const float* p = (const float*)d_in[1];   // [512,128,128] fp32
  float* scores  = (float*)d_ws;                              // 64 KB
  _Float16* qs   = (_Float16*)((char*)d_ws + 65536);          // 256 KB fp16 frags

  qprep_kernel<<<64, 256, 0, stream>>>(q, qs, (float*)d_out);
  scores_kernel<<<C / 2, 256, 0, stream>>>(p, qs, scores);
  loss_kernel<<<32, 256, 0, stream>>>(scores, (float*)d_out);
}